// Round 1
// baseline (1605.805 us; speedup 1.0000x reference)
//
#include <hip/hip_runtime.h>
#include <hip/hip_fp16.h>

// Wavefront-pipelined 20-layer ReLU RNN for MI355X — round 13.
// Base = round 12 (1104us). Change: 8 waves -> 4 waves (TPB 512->256),
// each wave owns 64 output columns (nt=4). Rationale: the shared MFMA
// operand (h fragments from lH, x fragments from bufX) is read once per
// wave -> redundancy factor == wave count. rocprof showed the LDS pipe
// ~85% busy (2x the MFMA pipe) with 7.07e7 conflict cycles; halving the
// wave count halves all shared-operand LDS reads and conflicts while
// keeping MFMA work identical (each b128 A-read now feeds 4 MFMAs).
// Weight regs double to wf[16][4] (256 VGPR-equiv, unified VGPR/AGPR
// file, launch_bounds(256,1) -> 512-reg budget). Per-thread ring/export
// traffic doubles: each thread handles rows m_e and m_e+8 (eidx, eidx+512).
// Ring format, sync protocol, XP-burst placement unchanged.

#define B_    128
#define T_    784
#define H_    256
#define L_    20
#define C_    10
#define G_    8      // batch slices
#define BM_   16     // batch rows per block
#define S_    4      // timesteps per superstep / ring slot
#define NS_   196    // T_/S_
#define SW_   280    // LDS row stride in halves (140 dwords = 12 mod 32)
#define RQWS_ 4096   // u64 words per ring slot (4 x 16 x 256 halves = 32KB)
#define TPB_  256
#define NT_   4      // 16-col n-tiles per wave

typedef _Float16 v8h __attribute__((ext_vector_type(8)));
typedef _Float16 v4h __attribute__((ext_vector_type(4)));
typedef float    v4f __attribute__((ext_vector_type(4)));
typedef unsigned long long u64;

union U64H { u64 u; _Float16 h[4]; };

__global__ __launch_bounds__(TPB_, 1)
void rnn_wavefront(const float* __restrict__ x,
                   const float* __restrict__ W_ih0,
                   const float* __restrict__ b_ih0,
                   const float* __restrict__ W_ih,
                   const float* __restrict__ b_ih,
                   const float* __restrict__ W_hh,
                   const float* __restrict__ b_hh,
                   const float* __restrict__ W_fc,
                   const float* __restrict__ b_fc,
                   float* __restrict__ out,
                   unsigned* __restrict__ prod,    // [L_][G_] supersteps complete
                   unsigned* __restrict__ cons,    // [L_][G_] supersteps consumed
                   u64* __restrict__ ring,         // [L_][G_][R][RQWS_]
                   int rmask)                      // R-1, R power of two
{
    const int l    = blockIdx.x >> 3;
    const int g    = blockIdx.x & 7;
    const int tid  = threadIdx.x;
    const int lane = tid & 63;
    const int wave = tid >> 6;          // 0..3
    const int quad = lane >> 4;
    const int s16  = lane & 15;
    const int nbase = wave * 64;        // each wave owns 64 output columns
    const int m_e  = tid >> 5;          // export/pf row (0..7; +8 for 2nd rep)
    const int n_e  = (tid & 31) * 8;    // export/pf col base (0..248)

    __shared__ __align__(16) _Float16 bufX[S_][BM_][SW_];  // staged input slot
    __shared__ __align__(16) _Float16 lH[2][BM_][SW_];     // own h, ping-pong

    for (int i = tid; i < 2 * BM_ * SW_; i += TPB_) (&lH[0][0][0])[i] = (_Float16)0.f;

    // ---- weight fragments: lane holds W[n = nbase+nt*16+s16][k = kt*32+quad*8 ..]
    // (A operand of the transposed GEMM h^T = W.h^T; one b128 LDS read of the
    //  shared operand now feeds NT_=4 MFMAs.)
    v8h wf[16][NT_];
#pragma unroll
    for (int kt = 0; kt < 16; ++kt) {
        const int k0 = kt * 32 + quad * 8;
#pragma unroll
        for (int nt = 0; nt < NT_; ++nt) {
            const int j = nbase + nt * 16 + s16;
            v8h w;
            if (kt < 8) {
                if (l == 0) {
#pragma unroll
                    for (int i = 0; i < 8; ++i) w[i] = (_Float16)0.f;
                } else {
                    const float* src = &W_ih[(((size_t)(l - 1) * H_) + j) * H_ + k0];
#pragma unroll
                    for (int i = 0; i < 8; ++i) w[i] = (_Float16)src[i];
                }
            } else {
                const float* src = &W_hh[(((size_t)l * H_) + j) * H_ + (k0 - 256)];
#pragma unroll
                for (int i = 0; i < 8; ++i) w[i] = (_Float16)src[i];
            }
            wf[kt][nt] = w;
        }
    }

    // bias/w0 indexed by the transposed C/D layout: lane owns rows
    // n = nbase + nt*16 + quad*4 + r  (r = 0..3), col m = s16.
    float bias[NT_][4], w0v[NT_][4];
#pragma unroll
    for (int nt = 0; nt < NT_; ++nt)
#pragma unroll
        for (int r = 0; r < 4; ++r) {
            const int j = nbase + nt * 16 + quad * 4 + r;
            bias[nt][r] = b_hh[l * H_ + j] + ((l == 0) ? b_ih0[j] : b_ih[(l - 1) * H_ + j]);
            w0v[nt][r]  = (l == 0) ? W_ih0[j] : 0.f;
        }

    unsigned* upprod = prod + ((l > 0 ? l - 1 : 0) * G_ + g);
    unsigned* myprod = prod + (l * G_ + g);
    unsigned* mycons = cons + (l * G_ + g);
    unsigned* dncons = cons + (((l < L_ - 1) ? l + 1 : l) * G_ + g);
    const unsigned R = (unsigned)rmask + 1u;
    u64* myring = ring + ((size_t)(l * G_ + g) * (size_t)R) * RQWS_;
    u64* upring = ring + ((size_t)((l > 0 ? l - 1 : 0) * G_ + g) * (size_t)R) * RQWS_;

    unsigned pSeen = 0, cSeen = 0;         // tid64 / tid128 private
    const size_t eidx = (size_t)m_e * 64 + (size_t)(tid & 31) * 2;  // u64 idx in slot
    // second row handled by this thread: row m_e+8 -> eidx + 8*64 = eidx + 512

    // ---- prologue (l>0): wait prod>=2, stage slot 0 into bufX (row-major) ----
    if (l > 0) {
        if (tid == 64) {
            while (pSeen < 2u) {
                pSeen = __hip_atomic_load(upprod, __ATOMIC_RELAXED,
                                          __HIP_MEMORY_SCOPE_AGENT);
                if (pSeen < 2u) __builtin_amdgcn_s_sleep(2);
            }
        }
        __syncthreads();
#pragma unroll
        for (int jj = 0; jj < S_; ++jj) {
            u64 v0 = __hip_atomic_load(upring + (size_t)jj * 1024 + eidx,
                                       __ATOMIC_RELAXED, __HIP_MEMORY_SCOPE_AGENT);
            u64 v1 = __hip_atomic_load(upring + (size_t)jj * 1024 + eidx + 1,
                                       __ATOMIC_RELAXED, __HIP_MEMORY_SCOPE_AGENT);
            u64 v2 = __hip_atomic_load(upring + (size_t)jj * 1024 + eidx + 512,
                                       __ATOMIC_RELAXED, __HIP_MEMORY_SCOPE_AGENT);
            u64 v3 = __hip_atomic_load(upring + (size_t)jj * 1024 + eidx + 513,
                                       __ATOMIC_RELAXED, __HIP_MEMORY_SCOPE_AGENT);
            *(u64*)&bufX[jj][m_e][n_e]         = v0;
            *(u64*)&bufX[jj][m_e][n_e + 4]     = v1;
            *(u64*)&bufX[jj][m_e + 8][n_e]     = v2;
            *(u64*)&bufX[jj][m_e + 8][n_e + 4] = v3;
        }
    }

    for (int s = 0; s < NS_; ++s) {
        const bool pfOK = (l > 0) && (s + 1 < NS_);
        u64 pfv[S_][4];
        v4h XPh[S_][NT_];   // hoisted X-half results + bias, fp16 (transposed layout)

#pragma unroll
        for (int j = 0; j < S_; ++j) {
            const int t = S_ * s + j;
            __syncthreads();   // step barrier (also drains vmem per compiler)

            if (j == 0) {
                if (tid == 0 && l > 0)
                    __hip_atomic_store(mycons, (unsigned)(s + 1), __ATOMIC_RELAXED,
                                       __HIP_MEMORY_SCOPE_AGENT); // slot s global free
                if (tid == 64 && pfOK) {            // guards pf of slot s+1 at j1
                    const unsigned tgt = (unsigned)(s + 2);
                    while (pSeen < tgt) {
                        pSeen = __hip_atomic_load(upprod, __ATOMIC_RELAXED,
                                                  __HIP_MEMORY_SCOPE_AGENT);
                        if (pSeen < tgt) __builtin_amdgcn_s_sleep(2);
                    }
                }
                if (tid == 128 && l < L_ - 1 && s >= (int)R) {  // guards exports into slot s
                    const unsigned tgt = (unsigned)(s - (int)R + 1);
                    while (cSeen < tgt) {
                        cSeen = __hip_atomic_load(dncons, __ATOMIC_RELAXED,
                                                  __HIP_MEMORY_SCOPE_AGENT);
                        if (cSeen < tgt) __builtin_amdgcn_s_sleep(2);
                    }
                }

                // ---- XP burst (transposed): XP[jj] = W_ih · X(4s+jj)^T + bias ----
                if (l > 0) {
#pragma unroll
                    for (int jj = 0; jj < S_; ++jj) {
                        v4f xpa[NT_];
#pragma unroll
                        for (int nt = 0; nt < NT_; ++nt)
                            xpa[nt] = (v4f){bias[nt][0], bias[nt][1],
                                            bias[nt][2], bias[nt][3]};
#pragma unroll
                        for (int kt = 0; kt < 8; ++kt) {
                            v8h a = *(const v8h*)&bufX[jj][s16][kt * 32 + quad * 8];
#pragma unroll
                            for (int nt = 0; nt < NT_; ++nt)
                                xpa[nt] = __builtin_amdgcn_mfma_f32_16x16x32_f16(
                                              wf[kt][nt], a, xpa[nt], 0, 0, 0);
                        }
#pragma unroll
                        for (int nt = 0; nt < NT_; ++nt)
#pragma unroll
                            for (int r = 0; r < 4; ++r)
                                XPh[jj][nt][r] = (_Float16)xpa[nt][r];
                    }
                } else {
                    // layer 0: XP[n][m] = bias[n] + x[m]*w0[n]; lane col m = s16
#pragma unroll
                    for (int jj = 0; jj < S_; ++jj) {
                        const float xv = x[(size_t)(g * BM_ + s16) * T_ + (S_ * s + jj)];
#pragma unroll
                        for (int nt = 0; nt < NT_; ++nt)
#pragma unroll
                            for (int r = 0; r < 4; ++r)
                                XPh[jj][nt][r] = (_Float16)(bias[nt][r] + xv * w0v[nt][r]);
                    }
                }
            }

            if (j == 1) {
                if (tid == 0 && l < L_ - 1 && s >= 1)
                    __hip_atomic_store(myprod, (unsigned)s, __ATOMIC_RELAXED,
                                       __HIP_MEMORY_SCOPE_AGENT); // slots 0..s-1 done
                if (pfOK) {   // prefetch slot s+1 -> regs (used at j3)
                    const u64* base = upring + (size_t)((s + 1) & rmask) * RQWS_;
#pragma unroll
                    for (int jj = 0; jj < S_; ++jj) {
                        pfv[jj][0] = __hip_atomic_load(base + (size_t)jj * 1024 + eidx,
                                                       __ATOMIC_RELAXED,
                                                       __HIP_MEMORY_SCOPE_AGENT);
                        pfv[jj][1] = __hip_atomic_load(base + (size_t)jj * 1024 + eidx + 1,
                                                       __ATOMIC_RELAXED,
                                                       __HIP_MEMORY_SCOPE_AGENT);
                        pfv[jj][2] = __hip_atomic_load(base + (size_t)jj * 1024 + eidx + 512,
                                                       __ATOMIC_RELAXED,
                                                       __HIP_MEMORY_SCOPE_AGENT);
                        pfv[jj][3] = __hip_atomic_load(base + (size_t)jj * 1024 + eidx + 513,
                                                       __ATOMIC_RELAXED,
                                                       __HIP_MEMORY_SCOPE_AGENT);
                    }
                }
            }

            // ---- export h(t-1) (lag 1 step; lH[t&1] holds h(t-1)) ----
            if (l < L_ - 1 && t > 0) {
                u64 e0 = *(const u64*)&lH[t & 1][m_e][n_e];
                u64 e1 = *(const u64*)&lH[t & 1][m_e][n_e + 4];
                u64 e2 = *(const u64*)&lH[t & 1][m_e + 8][n_e];
                u64 e3 = *(const u64*)&lH[t & 1][m_e + 8][n_e + 4];
                u64* d = myring + (size_t)(((t - 1) >> 2) & rmask) * RQWS_
                                + (size_t)((t - 1) & 3) * 1024 + eidx;
                __hip_atomic_store(d,       e0, __ATOMIC_RELAXED, __HIP_MEMORY_SCOPE_AGENT);
                __hip_atomic_store(d + 1,   e1, __ATOMIC_RELAXED, __HIP_MEMORY_SCOPE_AGENT);
                __hip_atomic_store(d + 512, e2, __ATOMIC_RELAXED, __HIP_MEMORY_SCOPE_AGENT);
                __hip_atomic_store(d + 513, e3, __ATOMIC_RELAXED, __HIP_MEMORY_SCOPE_AGENT);
            }

            // ---- serial h-MFMA (transposed): D = W_hh · h(t-1)^T, 32 MFMA ----
            v4f acc[NT_];
#pragma unroll
            for (int nt = 0; nt < NT_; ++nt) acc[nt] = (v4f){0.f, 0.f, 0.f, 0.f};
#pragma unroll
            for (int kt = 0; kt < 8; ++kt) {
                v8h a = *(const v8h*)&lH[t & 1][s16][kt * 32 + quad * 8];
#pragma unroll
                for (int nt = 0; nt < NT_; ++nt)
                    acc[nt] = __builtin_amdgcn_mfma_f32_16x16x32_f16(
                                  wf[8 + kt][nt], a, acc[nt], 0, 0, 0);
            }

            // ---- epilogue: relu(XP + acc) -> lH[(t+1)&1]; lane holds
            // D[n = nbase+nt*16+quad*4+r][m = s16] -> ONE b64 write per nt ----
#pragma unroll
            for (int nt = 0; nt < NT_; ++nt) {
                U64H pk;
#pragma unroll
                for (int r = 0; r < 4; ++r) {
                    float v = (float)XPh[j][nt][r] + acc[nt][r];
                    v = fmaxf(v, 0.f);
                    pk.h[r] = (_Float16)v;
                }
                *(u64*)&lH[(t + 1) & 1][s16][nbase + nt * 16 + quad * 4] = pk.u;
            }

            if (j == S_ - 1) {
                __syncthreads();   // all waves done with bufX of this superstep
                if (pfOK) {        // unscramble: pure ds_write_b64, no extraction
#pragma unroll
                    for (int jj = 0; jj < S_; ++jj) {
                        *(u64*)&bufX[jj][m_e][n_e]         = pfv[jj][0];
                        *(u64*)&bufX[jj][m_e][n_e + 4]     = pfv[jj][1];
                        *(u64*)&bufX[jj][m_e + 8][n_e]     = pfv[jj][2];
                        *(u64*)&bufX[jj][m_e + 8][n_e + 4] = pfv[jj][3];
                    }
                }
            }
        }
    }

    if (l < L_ - 1) {
        // tail: export h(T-1) (in lH[0]: (783+1)&1), drain, publish all done
        u64 e0 = *(const u64*)&lH[0][m_e][n_e];
        u64 e1 = *(const u64*)&lH[0][m_e][n_e + 4];
        u64 e2 = *(const u64*)&lH[0][m_e + 8][n_e];
        u64 e3 = *(const u64*)&lH[0][m_e + 8][n_e + 4];
        u64* d = myring + (size_t)(((T_ - 1) >> 2) & rmask) * RQWS_
                        + (size_t)3 * 1024 + eidx;
        __hip_atomic_store(d,       e0, __ATOMIC_RELAXED, __HIP_MEMORY_SCOPE_AGENT);
        __hip_atomic_store(d + 1,   e1, __ATOMIC_RELAXED, __HIP_MEMORY_SCOPE_AGENT);
        __hip_atomic_store(d + 512, e2, __ATOMIC_RELAXED, __HIP_MEMORY_SCOPE_AGENT);
        __hip_atomic_store(d + 513, e3, __ATOMIC_RELAXED, __HIP_MEMORY_SCOPE_AGENT);
        __syncthreads();   // drains the exports (vmcnt(0) before s_barrier)
        if (tid == 0)
            __hip_atomic_store(myprod, (unsigned)NS_, __ATOMIC_RELAXED,
                               __HIP_MEMORY_SCOPE_AGENT);
    } else {
        __syncthreads();
        // final FC: out[b] = h_T[b] @ W_fc^T + b_fc; h_T in lH[0]
        if (tid < BM_ * C_) {
            const int bl = tid / C_;
            const int c  = tid % C_;
            float sum = b_fc[c];
            for (int k = 0; k < H_; ++k) sum += (float)lH[0][bl][k] * W_fc[c * H_ + k];
            out[(size_t)(g * BM_ + bl) * C_ + c] = sum;
        }
    }
}

extern "C" void kernel_launch(void* const* d_in, const int* in_sizes, int n_in,
                              void* d_out, int out_size, void* d_ws, size_t ws_size,
                              hipStream_t stream) {
    const float* x     = (const float*)d_in[0];
    const float* W_ih0 = (const float*)d_in[1];
    const float* b_ih0 = (const float*)d_in[2];
    const float* W_ih  = (const float*)d_in[3];
    const float* b_ih  = (const float*)d_in[4];
    const float* W_hh  = (const float*)d_in[5];
    const float* b_hh  = (const float*)d_in[6];
    const float* W_fc  = (const float*)d_in[7];
    const float* b_fc  = (const float*)d_in[8];
    float* out = (float*)d_out;

    const size_t cntBytes = (size_t)L_ * G_ * sizeof(unsigned);   // 640 B each
    unsigned* prod = (unsigned*)d_ws;
    unsigned* cons = (unsigned*)((char*)d_ws + cntBytes);
    u64* ring      = (u64*)((char*)d_ws + 2 * cntBytes);

    // ring slots per link, by available workspace (32 KB per slot per link)
    const size_t slotBytes = (size_t)RQWS_ * 8;                   // 32 KB
    const size_t base = 2 * cntBytes;
    int R = 4;                                                    // 21 MB
    if (ws_size >= base + (size_t)L_ * G_ * 16 * slotBytes) R = 16;      // 84 MB
    else if (ws_size >= base + (size_t)L_ * G_ * 8 * slotBytes) R = 8;   // 42 MB

    hipMemsetAsync(d_ws, 0, 2 * cntBytes, stream);

    rnn_wavefront<<<dim3(L_ * G_), dim3(TPB_), 0, stream>>>(
        x, W_ih0, b_ih0, W_ih, b_ih, W_hh, b_hh, W_fc, b_fc,
        out, prod, cons, ring, R - 1);
}

// Round 2
// 1130.879 us; speedup vs baseline: 1.4200x; 1.4200x over previous
//
#include <hip/hip_runtime.h>
#include <hip/hip_fp16.h>

// Wavefront-pipelined 20-layer ReLU RNN for MI355X — round 14.
// Base = round 12 (best: 1104us; 8 waves, nt=2). Round 13 (4 waves) FAILED:
// conflicts halved as predicted but dur +45% -> kernel is latency-bound, not
// LDS-throughput-bound. Reverted to 8 waves.
// Change this round: __syncthreads() in the hot loop emits
// s_waitcnt vmcnt(0) before s_barrier, which (a) drains the ring-export
// stores EVERY timestep (~200-400cy ack) and (b) drains the slot-prefetch
// loads at the j==2 barrier, defeating the j1->j3 prefetch distance
// (~500-900cy L3/HBM latency exposed per superstep). Replace hot-loop
// barriers with raw s_barrier + lgkmcnt(0)-only (LDS exchange is the only
// per-step cross-wave dependency). Keep ONE vmcnt(0)+lgkmcnt(0) drain per
// superstep at the top-of-j==1 barrier: that is the point that must
// guarantee all waves' slot-(s-1) exports are visible before tid0 publishes
// myprod=s. Ring reads stay ordered via data-dep (pfv consumed at j==3,
// two barriers before the mycons publish). Everything else = r12.

#define B_    128
#define T_    784
#define H_    256
#define L_    20
#define C_    10
#define G_    8      // batch slices
#define BM_   16     // batch rows per block
#define S_    4      // timesteps per superstep / ring slot
#define NS_   196    // T_/S_
#define SW_   280    // LDS row stride in halves (140 dwords = 12 mod 32)
#define RQWS_ 4096   // u64 words per ring slot (4 x 16 x 256 halves = 32KB)
#define TPB_  512

typedef _Float16 v8h __attribute__((ext_vector_type(8)));
typedef _Float16 v4h __attribute__((ext_vector_type(4)));
typedef float    v4f __attribute__((ext_vector_type(4)));
typedef unsigned long long u64;

union U64H { u64 u; _Float16 h[4]; };

// Raw barrier, LDS-ordering only: each wave drains its own ds ops, then
// rendezvous. No vmcnt drain -> export stores / pf loads stay in flight.
__device__ __forceinline__ void bar_lds() {
    asm volatile("s_waitcnt lgkmcnt(0)" ::: "memory");
    __builtin_amdgcn_s_barrier();
    asm volatile("" ::: "memory");
}
// Full drain barrier: once per superstep (top of j==1), guarantees all
// waves' ring exports are globally visible before the prod publish.
__device__ __forceinline__ void bar_full() {
    asm volatile("s_waitcnt vmcnt(0) lgkmcnt(0)" ::: "memory");
    __builtin_amdgcn_s_barrier();
    asm volatile("" ::: "memory");
}

__global__ __launch_bounds__(TPB_, 2)
void rnn_wavefront(const float* __restrict__ x,
                   const float* __restrict__ W_ih0,
                   const float* __restrict__ b_ih0,
                   const float* __restrict__ W_ih,
                   const float* __restrict__ b_ih,
                   const float* __restrict__ W_hh,
                   const float* __restrict__ b_hh,
                   const float* __restrict__ W_fc,
                   const float* __restrict__ b_fc,
                   float* __restrict__ out,
                   unsigned* __restrict__ prod,    // [L_][G_] supersteps complete
                   unsigned* __restrict__ cons,    // [L_][G_] supersteps consumed
                   u64* __restrict__ ring,         // [L_][G_][R][RQWS_]
                   int rmask)                      // R-1, R power of two
{
    const int l    = blockIdx.x >> 3;
    const int g    = blockIdx.x & 7;
    const int tid  = threadIdx.x;
    const int lane = tid & 63;
    const int wave = tid >> 6;          // 0..7
    const int quad = lane >> 4;
    const int s16  = lane & 15;
    const int nbase = wave * 32;        // each wave owns 32 output columns
    const int m_e  = tid >> 5;          // export/pf row (0..15)
    const int n_e  = (tid & 31) * 8;    // export/pf col base (0..248)

    __shared__ __align__(16) _Float16 bufX[S_][BM_][SW_];  // staged input slot
    __shared__ __align__(16) _Float16 lH[2][BM_][SW_];     // own h, ping-pong

    for (int i = tid; i < 2 * BM_ * SW_; i += TPB_) (&lH[0][0][0])[i] = (_Float16)0.f;

    // ---- weight fragments: lane holds W[n = nbase+nt*16+s16][k = kt*32+quad*8 ..]
    v8h wf[16][2];
#pragma unroll
    for (int kt = 0; kt < 16; ++kt) {
        const int k0 = kt * 32 + quad * 8;
#pragma unroll
        for (int nt = 0; nt < 2; ++nt) {
            const int j = nbase + nt * 16 + s16;
            v8h w;
            if (kt < 8) {
                if (l == 0) {
#pragma unroll
                    for (int i = 0; i < 8; ++i) w[i] = (_Float16)0.f;
                } else {
                    const float* src = &W_ih[(((size_t)(l - 1) * H_) + j) * H_ + k0];
#pragma unroll
                    for (int i = 0; i < 8; ++i) w[i] = (_Float16)src[i];
                }
            } else {
                const float* src = &W_hh[(((size_t)l * H_) + j) * H_ + (k0 - 256)];
#pragma unroll
                for (int i = 0; i < 8; ++i) w[i] = (_Float16)src[i];
            }
            wf[kt][nt] = w;
        }
    }

    // bias/w0 indexed by the transposed C/D layout: lane owns rows
    // n = nbase + nt*16 + quad*4 + r  (r = 0..3), col m = s16.
    float bias[2][4], w0v[2][4];
#pragma unroll
    for (int nt = 0; nt < 2; ++nt)
#pragma unroll
        for (int r = 0; r < 4; ++r) {
            const int j = nbase + nt * 16 + quad * 4 + r;
            bias[nt][r] = b_hh[l * H_ + j] + ((l == 0) ? b_ih0[j] : b_ih[(l - 1) * H_ + j]);
            w0v[nt][r]  = (l == 0) ? W_ih0[j] : 0.f;
        }

    unsigned* upprod = prod + ((l > 0 ? l - 1 : 0) * G_ + g);
    unsigned* myprod = prod + (l * G_ + g);
    unsigned* mycons = cons + (l * G_ + g);
    unsigned* dncons = cons + (((l < L_ - 1) ? l + 1 : l) * G_ + g);
    const unsigned R = (unsigned)rmask + 1u;
    u64* myring = ring + ((size_t)(l * G_ + g) * (size_t)R) * RQWS_;
    u64* upring = ring + ((size_t)((l > 0 ? l - 1 : 0) * G_ + g) * (size_t)R) * RQWS_;

    unsigned pSeen = 0, cSeen = 0;         // tid64 / tid128 private
    const size_t eidx = (size_t)m_e * 64 + (size_t)(tid & 31) * 2;  // u64 idx in slot

    // ---- prologue (l>0): wait prod>=2, stage slot 0 into bufX (row-major) ----
    if (l > 0) {
        if (tid == 64) {
            while (pSeen < 2u) {
                pSeen = __hip_atomic_load(upprod, __ATOMIC_RELAXED,
                                          __HIP_MEMORY_SCOPE_AGENT);
                if (pSeen < 2u) __builtin_amdgcn_s_sleep(2);
            }
        }
        __syncthreads();
#pragma unroll
        for (int jj = 0; jj < S_; ++jj) {
            u64 v0 = __hip_atomic_load(upring + (size_t)jj * 1024 + eidx,
                                       __ATOMIC_RELAXED, __HIP_MEMORY_SCOPE_AGENT);
            u64 v1 = __hip_atomic_load(upring + (size_t)jj * 1024 + eidx + 1,
                                       __ATOMIC_RELAXED, __HIP_MEMORY_SCOPE_AGENT);
            *(u64*)&bufX[jj][m_e][n_e]     = v0;
            *(u64*)&bufX[jj][m_e][n_e + 4] = v1;
        }
    }

    for (int s = 0; s < NS_; ++s) {
        const bool pfOK = (l > 0) && (s + 1 < NS_);
        u64 pfv[S_][2];
        v4h XPh[S_][2];   // hoisted X-half results + bias, fp16 (transposed layout)

#pragma unroll
        for (int j = 0; j < S_; ++j) {
            const int t = S_ * s + j;
            // step barrier: LDS-only, except j==1 (full drain, guards the
            // myprod publish just below -> slot s-1 exports visible).
            if (j == 1) bar_full(); else bar_lds();

            if (j == 0) {
                if (tid == 0 && l > 0)
                    __hip_atomic_store(mycons, (unsigned)(s + 1), __ATOMIC_RELAXED,
                                       __HIP_MEMORY_SCOPE_AGENT); // slot s global free
                if (tid == 64 && pfOK) {            // guards pf of slot s+1 at j1
                    const unsigned tgt = (unsigned)(s + 2);
                    while (pSeen < tgt) {
                        pSeen = __hip_atomic_load(upprod, __ATOMIC_RELAXED,
                                                  __HIP_MEMORY_SCOPE_AGENT);
                        if (pSeen < tgt) __builtin_amdgcn_s_sleep(2);
                    }
                }
                if (tid == 128 && l < L_ - 1 && s >= (int)R) {  // guards exports into slot s
                    const unsigned tgt = (unsigned)(s - (int)R + 1);
                    while (cSeen < tgt) {
                        cSeen = __hip_atomic_load(dncons, __ATOMIC_RELAXED,
                                                  __HIP_MEMORY_SCOPE_AGENT);
                        if (cSeen < tgt) __builtin_amdgcn_s_sleep(2);
                    }
                }

                // ---- XP burst (transposed): XP[jj] = W_ih · X(4s+jj)^T + bias ----
                if (l > 0) {
                    v4f xpa[S_][2];
#pragma unroll
                    for (int jj = 0; jj < S_; ++jj)
#pragma unroll
                        for (int nt = 0; nt < 2; ++nt)
                            xpa[jj][nt] = (v4f){bias[nt][0], bias[nt][1],
                                                bias[nt][2], bias[nt][3]};
#pragma unroll
                    for (int jj = 0; jj < S_; ++jj) {
#pragma unroll
                        for (int kt = 0; kt < 8; ++kt) {
                            v8h a = *(const v8h*)&bufX[jj][s16][kt * 32 + quad * 8];
                            xpa[jj][0] = __builtin_amdgcn_mfma_f32_16x16x32_f16(wf[kt][0], a, xpa[jj][0], 0, 0, 0);
                            xpa[jj][1] = __builtin_amdgcn_mfma_f32_16x16x32_f16(wf[kt][1], a, xpa[jj][1], 0, 0, 0);
                        }
                    }
#pragma unroll
                    for (int jj = 0; jj < S_; ++jj)
#pragma unroll
                        for (int nt = 0; nt < 2; ++nt)
#pragma unroll
                            for (int r = 0; r < 4; ++r)
                                XPh[jj][nt][r] = (_Float16)xpa[jj][nt][r];
                } else {
                    // layer 0: XP[n][m] = bias[n] + x[m]*w0[n]; lane col m = s16
#pragma unroll
                    for (int jj = 0; jj < S_; ++jj) {
                        const float xv = x[(size_t)(g * BM_ + s16) * T_ + (S_ * s + jj)];
#pragma unroll
                        for (int nt = 0; nt < 2; ++nt)
#pragma unroll
                            for (int r = 0; r < 4; ++r)
                                XPh[jj][nt][r] = (_Float16)(bias[nt][r] + xv * w0v[nt][r]);
                    }
                }
            }

            if (j == 1) {
                if (tid == 0 && l < L_ - 1 && s >= 1)
                    __hip_atomic_store(myprod, (unsigned)s, __ATOMIC_RELAXED,
                                       __HIP_MEMORY_SCOPE_AGENT); // slots 0..s-1 done
                if (pfOK) {   // prefetch slot s+1 -> regs (used at j3)
                    const u64* base = upring + (size_t)((s + 1) & rmask) * RQWS_;
#pragma unroll
                    for (int jj = 0; jj < S_; ++jj) {
                        pfv[jj][0] = __hip_atomic_load(base + (size_t)jj * 1024 + eidx,
                                                       __ATOMIC_RELAXED,
                                                       __HIP_MEMORY_SCOPE_AGENT);
                        pfv[jj][1] = __hip_atomic_load(base + (size_t)jj * 1024 + eidx + 1,
                                                       __ATOMIC_RELAXED,
                                                       __HIP_MEMORY_SCOPE_AGENT);
                    }
                }
            }

            // ---- export h(t-1) (lag 1 step; lH[t&1] holds h(t-1)) ----
            if (l < L_ - 1 && t > 0) {
                u64 e0 = *(const u64*)&lH[t & 1][m_e][n_e];
                u64 e1 = *(const u64*)&lH[t & 1][m_e][n_e + 4];
                u64* d = myring + (size_t)(((t - 1) >> 2) & rmask) * RQWS_
                                + (size_t)((t - 1) & 3) * 1024 + eidx;
                __hip_atomic_store(d,     e0, __ATOMIC_RELAXED, __HIP_MEMORY_SCOPE_AGENT);
                __hip_atomic_store(d + 1, e1, __ATOMIC_RELAXED, __HIP_MEMORY_SCOPE_AGENT);
            }

            // ---- serial h-MFMA (transposed): D = W_hh · h(t-1)^T, 16 MFMA ----
            v4f acc0 = (v4f){0.f, 0.f, 0.f, 0.f};
            v4f acc1 = (v4f){0.f, 0.f, 0.f, 0.f};
#pragma unroll
            for (int kt = 8; kt < 16; ++kt) {
                v8h a = *(const v8h*)&lH[t & 1][s16][(kt - 8) * 32 + quad * 8];
                acc0 = __builtin_amdgcn_mfma_f32_16x16x32_f16(wf[kt][0], a, acc0, 0, 0, 0);
                acc1 = __builtin_amdgcn_mfma_f32_16x16x32_f16(wf[kt][1], a, acc1, 0, 0, 0);
            }

            // ---- epilogue: relu(XP + acc) -> lH[(t+1)&1]; lane holds
            // D[n = nbase+nt*16+quad*4+r][m = s16] -> ONE b64 write per nt ----
#pragma unroll
            for (int nt = 0; nt < 2; ++nt) {
                const v4f av = nt ? acc1 : acc0;
                U64H pk;
#pragma unroll
                for (int r = 0; r < 4; ++r) {
                    float v = (float)XPh[j][nt][r] + av[r];
                    v = fmaxf(v, 0.f);
                    pk.h[r] = (_Float16)v;
                }
                *(u64*)&lH[(t + 1) & 1][s16][nbase + nt * 16 + quad * 4] = pk.u;
            }

            if (j == S_ - 1) {
                bar_lds();         // all waves done with bufX of this superstep
                if (pfOK) {        // unscramble: pure ds_write_b64, no extraction
#pragma unroll
                    for (int jj = 0; jj < S_; ++jj) {
                        *(u64*)&bufX[jj][m_e][n_e]     = pfv[jj][0];
                        *(u64*)&bufX[jj][m_e][n_e + 4] = pfv[jj][1];
                    }
                }
            }
        }
    }

    if (l < L_ - 1) {
        // tail: export h(T-1) (in lH[0]: (783+1)&1), drain, publish all done
        u64 e0 = *(const u64*)&lH[0][m_e][n_e];
        u64 e1 = *(const u64*)&lH[0][m_e][n_e + 4];
        u64* d = myring + (size_t)(((T_ - 1) >> 2) & rmask) * RQWS_
                        + (size_t)3 * 1024 + eidx;
        __hip_atomic_store(d,     e0, __ATOMIC_RELAXED, __HIP_MEMORY_SCOPE_AGENT);
        __hip_atomic_store(d + 1, e1, __ATOMIC_RELAXED, __HIP_MEMORY_SCOPE_AGENT);
        __syncthreads();   // full drain (vmcnt(0)) before publishing final prod
        if (tid == 0)
            __hip_atomic_store(myprod, (unsigned)NS_, __ATOMIC_RELAXED,
                               __HIP_MEMORY_SCOPE_AGENT);
    } else {
        __syncthreads();
        // final FC: out[b] = h_T[b] @ W_fc^T + b_fc; h_T in lH[0]
        if (tid < BM_ * C_) {
            const int bl = tid / C_;
            const int c  = tid % C_;
            float sum = b_fc[c];
            for (int k = 0; k < H_; ++k) sum += (float)lH[0][bl][k] * W_fc[c * H_ + k];
            out[(size_t)(g * BM_ + bl) * C_ + c] = sum;
        }
    }
}

extern "C" void kernel_launch(void* const* d_in, const int* in_sizes, int n_in,
                              void* d_out, int out_size, void* d_ws, size_t ws_size,
                              hipStream_t stream) {
    const float* x     = (const float*)d_in[0];
    const float* W_ih0 = (const float*)d_in[1];
    const float* b_ih0 = (const float*)d_in[2];
    const float* W_ih  = (const float*)d_in[3];
    const float* b_ih  = (const float*)d_in[4];
    const float* W_hh  = (const float*)d_in[5];
    const float* b_hh  = (const float*)d_in[6];
    const float* W_fc  = (const float*)d_in[7];
    const float* b_fc  = (const float*)d_in[8];
    float* out = (float*)d_out;

    const size_t cntBytes = (size_t)L_ * G_ * sizeof(unsigned);   // 640 B each
    unsigned* prod = (unsigned*)d_ws;
    unsigned* cons = (unsigned*)((char*)d_ws + cntBytes);
    u64* ring      = (u64*)((char*)d_ws + 2 * cntBytes);

    // ring slots per link, by available workspace (32 KB per slot per link)
    const size_t slotBytes = (size_t)RQWS_ * 8;                   // 32 KB
    const size_t base = 2 * cntBytes;
    int R = 4;                                                    // 21 MB
    if (ws_size >= base + (size_t)L_ * G_ * 16 * slotBytes) R = 16;      // 84 MB
    else if (ws_size >= base + (size_t)L_ * G_ * 8 * slotBytes) R = 8;   // 42 MB

    hipMemsetAsync(d_ws, 0, 2 * cntBytes, stream);

    rnn_wavefront<<<dim3(L_ * G_), dim3(TPB_), 0, stream>>>(
        x, W_ih0, b_ih0, W_ih, b_ih, W_hh, b_hh, W_fc, b_fc,
        out, prod, cons, ring, R - 1);
}